// Round 1
// baseline (705.405 us; speedup 1.0000x reference)
//
#include <hip/hip_runtime.h>
#include <hip/hip_bf16.h>

#define D_IN 128
#define D_H  256

// ---------------- CSR build ----------------

__global__ void hist_k(const int* __restrict__ dst, int* __restrict__ deg, int E) {
    for (int e = blockIdx.x * blockDim.x + threadIdx.x; e < E; e += gridDim.x * blockDim.x)
        atomicAdd(&deg[dst[e]], 1);
}

// single-block exclusive scan over n elements (n ~ 50000)
__global__ __launch_bounds__(1024) void scan_k(const int* __restrict__ deg,
                                               int* __restrict__ row_ptr, int n) {
    __shared__ int part[1024];
    const int tid = threadIdx.x;
    const int chunk = (n + 1023) / 1024;
    const int start = tid * chunk;
    const int end = min(start + chunk, n);
    int s = 0;
    for (int i = start; i < end; ++i) s += deg[i];
    part[tid] = s;
    __syncthreads();
    // Hillis-Steele inclusive scan over 1024 partials
    for (int off = 1; off < 1024; off <<= 1) {
        int v = 0;
        if (tid >= off) v = part[tid - off];
        __syncthreads();
        part[tid] += v;
        __syncthreads();
    }
    int base = (tid == 0) ? 0 : part[tid - 1];
    for (int i = start; i < end; ++i) {
        row_ptr[i] = base;
        base += deg[i];
    }
    if (tid == 1023) row_ptr[n] = part[1023];
}

__global__ void scatter_k(const int* __restrict__ src, const int* __restrict__ dst,
                          const int* __restrict__ row_ptr, int* __restrict__ cursor,
                          int* __restrict__ col, int E) {
    for (int e = blockIdx.x * blockDim.x + threadIdx.x; e < E; e += gridDim.x * blockDim.x) {
        int d = dst[e];
        int r = atomicAdd(&cursor[d], 1);
        col[row_ptr[d] + r] = src[e];
    }
}

// ---------------- mean aggregation ----------------
// one block per node; blockDim.x == d (128 or 256)
__global__ void aggregate_k(const float* __restrict__ X, const int* __restrict__ col,
                            const int* __restrict__ rp, float* __restrict__ out, int d) {
    const int n = blockIdx.x;
    const int s = rp[n], e = rp[n + 1];
    const int t = threadIdx.x;
    float acc = 0.f;
    int j = s;
    for (; j + 1 < e; j += 2) {                     // 2-way unroll for MLP
        int c0 = col[j], c1 = col[j + 1];
        acc += X[(size_t)c0 * d + t];
        acc += X[(size_t)c1 * d + t];
    }
    if (j < e) {
        int c0 = col[j];
        acc += X[(size_t)c0 * d + t];
    }
    float dg = (float)(e - s);
    out[(size_t)n * d + t] = acc / fmaxf(dg, 1.0f);
}

// ---------------- dual-input fp32 GEMM ----------------
// out[m][n] = relu( sum_k A[m][k]*WA[n][k] + sum_k B[m][k]*WB[n][k] + bias[n] )
// N = 256 fixed, tile 64x64, block 256 threads, 4x4 microtile
template <int K, bool RELU>
__global__ __launch_bounds__(256) void gemm_dual_k(
    const float* __restrict__ A, const float* __restrict__ WA,
    const float* __restrict__ B, const float* __restrict__ WB,
    const float* __restrict__ bias, float* __restrict__ out, int M) {
    __shared__ float sA[32][68];
    __shared__ float sW[32][68];
    const int tid = threadIdx.x;
    const int m0 = blockIdx.x * 64;
    const int n0 = blockIdx.y * 64;
    const int lrow = tid >> 2;          // 0..63
    const int kg = (tid & 3) * 8;       // 0,8,16,24
    const int tm = tid >> 4;            // 0..15
    const int tn = tid & 15;            // 0..15

    float acc[4][4];
#pragma unroll
    for (int i = 0; i < 4; ++i)
#pragma unroll
        for (int j = 0; j < 4; ++j) acc[i][j] = 0.f;

    for (int phase = 0; phase < 2; ++phase) {
        const float* Ap = phase ? B : A;
        const float* Wp = phase ? WB : WA;
        for (int k0 = 0; k0 < K; k0 += 32) {
            int gr = m0 + lrow;
            if (gr >= M) gr = M - 1;    // clamp (stores are guarded)
            const float4 va0 = *(const float4*)(Ap + (size_t)gr * K + k0 + kg);
            const float4 va1 = *(const float4*)(Ap + (size_t)gr * K + k0 + kg + 4);
            const float4 vw0 = *(const float4*)(Wp + (size_t)(n0 + lrow) * K + k0 + kg);
            const float4 vw1 = *(const float4*)(Wp + (size_t)(n0 + lrow) * K + k0 + kg + 4);
            __syncthreads();            // previous iteration's reads done
            sA[kg + 0][lrow] = va0.x; sA[kg + 1][lrow] = va0.y;
            sA[kg + 2][lrow] = va0.z; sA[kg + 3][lrow] = va0.w;
            sA[kg + 4][lrow] = va1.x; sA[kg + 5][lrow] = va1.y;
            sA[kg + 6][lrow] = va1.z; sA[kg + 7][lrow] = va1.w;
            sW[kg + 0][lrow] = vw0.x; sW[kg + 1][lrow] = vw0.y;
            sW[kg + 2][lrow] = vw0.z; sW[kg + 3][lrow] = vw0.w;
            sW[kg + 4][lrow] = vw1.x; sW[kg + 5][lrow] = vw1.y;
            sW[kg + 6][lrow] = vw1.z; sW[kg + 7][lrow] = vw1.w;
            __syncthreads();
#pragma unroll
            for (int kk = 0; kk < 32; ++kk) {
                const float4 a = *(const float4*)&sA[kk][tm * 4];
                const float4 w = *(const float4*)&sW[kk][tn * 4];
                const float av[4] = {a.x, a.y, a.z, a.w};
                const float wv[4] = {w.x, w.y, w.z, w.w};
#pragma unroll
                for (int i = 0; i < 4; ++i)
#pragma unroll
                    for (int j = 0; j < 4; ++j) acc[i][j] += av[i] * wv[j];
            }
        }
    }

#pragma unroll
    for (int i = 0; i < 4; ++i) {
        const int m = m0 + tm * 4 + i;
        if (m < M) {
            float4 o;
            float b0 = bias[n0 + tn * 4 + 0];
            float b1 = bias[n0 + tn * 4 + 1];
            float b2 = bias[n0 + tn * 4 + 2];
            float b3 = bias[n0 + tn * 4 + 3];
            o.x = acc[i][0] + b0; o.y = acc[i][1] + b1;
            o.z = acc[i][2] + b2; o.w = acc[i][3] + b3;
            if (RELU) {
                o.x = fmaxf(o.x, 0.f); o.y = fmaxf(o.y, 0.f);
                o.z = fmaxf(o.z, 0.f); o.w = fmaxf(o.w, 0.f);
            }
            *(float4*)(out + (size_t)m * 256 + n0 + tn * 4) = o;
        }
    }
}

// ---------------- head: out[m] = dot(h2[m,:256], hw) + hb ----------------
__global__ __launch_bounds__(256) void head_k(const float* __restrict__ h2,
                                              const float* __restrict__ hw,
                                              const float* __restrict__ hb,
                                              float* __restrict__ out, int M) {
    const int wave = threadIdx.x >> 6;
    const int lane = threadIdx.x & 63;
    const int n = blockIdx.x * 4 + wave;
    if (n >= M) return;
    const float* row = h2 + (size_t)n * 256;
    float s = 0.f;
#pragma unroll
    for (int i = 0; i < 4; ++i) {
        int c = lane + i * 64;
        s += row[c] * hw[c];
    }
#pragma unroll
    for (int off = 32; off > 0; off >>= 1) s += __shfl_down(s, off, 64);
    if (lane == 0) out[n] = s + hb[0];
}

// ---------------- launch ----------------
extern "C" void kernel_launch(void* const* d_in, const int* in_sizes, int n_in,
                              void* d_out, int out_size, void* d_ws, size_t ws_size,
                              hipStream_t stream) {
    const float* x    = (const float*)d_in[0];
    const int*   ei   = (const int*)d_in[1];
    const float* W1l  = (const float*)d_in[2];
    const float* b1   = (const float*)d_in[3];
    const float* W1r  = (const float*)d_in[4];
    const float* W2l  = (const float*)d_in[5];
    const float* b2   = (const float*)d_in[6];
    const float* W2r  = (const float*)d_in[7];
    const float* hw   = (const float*)d_in[8];
    const float* hb   = (const float*)d_in[9];
    float* out = (float*)d_out;

    const int M = in_sizes[0] / D_IN;       // 50000
    const int E = in_sizes[1] / 2;          // 800000
    const int* src = ei;
    const int* dst = ei + E;

    size_t off = 0;
    auto alloc = [&](size_t bytes) -> void* {
        void* p = (char*)d_ws + off;
        off += (bytes + 255) & ~(size_t)255;
        return p;
    };
    int*   deg    = (int*)alloc((size_t)M * 4);
    int*   rp     = (int*)alloc((size_t)(M + 1) * 4);
    int*   cursor = (int*)alloc((size_t)M * 4);
    int*   col    = (int*)alloc((size_t)E * 4);
    float* mean1  = (float*)alloc((size_t)M * D_IN * 4);
    float* h1     = (float*)alloc((size_t)M * D_H * 4);
    float* mean2  = (float*)alloc((size_t)M * D_H * 4);
    float* h2     = (float*)alloc((size_t)M * D_H * 4);

    hipMemsetAsync(deg, 0, (size_t)M * 4, stream);
    hipMemsetAsync(cursor, 0, (size_t)M * 4, stream);

    hist_k<<<512, 256, 0, stream>>>(dst, deg, E);
    scan_k<<<1, 1024, 0, stream>>>(deg, rp, M);
    scatter_k<<<512, 256, 0, stream>>>(src, dst, rp, cursor, col, E);

    // layer 1
    aggregate_k<<<M, D_IN, 0, stream>>>(x, col, rp, mean1, D_IN);
    {
        dim3 grid((M + 63) / 64, 4);
        gemm_dual_k<128, true><<<grid, 256, 0, stream>>>(mean1, W1l, x, W1r, b1, h1, M);
    }
    // layer 2
    aggregate_k<<<M, D_H, 0, stream>>>(h1, col, rp, mean2, D_H);
    {
        dim3 grid((M + 63) / 64, 4);
        gemm_dual_k<256, true><<<grid, 256, 0, stream>>>(mean2, W2l, h1, W2r, b2, h2, M);
    }
    // head
    head_k<<<(M + 3) / 4, 256, 0, stream>>>(h2, hw, hb, out, M);
}

// Round 2
// 472.626 us; speedup vs baseline: 1.4925x; 1.4925x over previous
//
#include <hip/hip_runtime.h>
#include <hip/hip_bf16.h>

#define D_IN 128
#define D_H  256

typedef __attribute__((ext_vector_type(8))) short short8;   // 8 bf16 (4 VGPRs)
typedef __attribute__((ext_vector_type(4))) float floatx4;  // MFMA C/D frag

__device__ __forceinline__ unsigned short f2bf(float f) {
    __hip_bfloat16 h = __float2bfloat16(f);
    return *reinterpret_cast<unsigned short*>(&h);
}
__device__ __forceinline__ float bf2f(unsigned short s) {
    union { unsigned int u; float f; } v;
    v.u = ((unsigned int)s) << 16;
    return v.f;
}

// ---------------- fp32 -> bf16 convert (n multiple of 4) ----------------
__global__ void f2bf_k(const float* __restrict__ in, unsigned short* __restrict__ out, int n4) {
    int i = blockIdx.x * blockDim.x + threadIdx.x;
    if (i < n4) {
        float4 v = ((const float4*)in)[i];
        ushort4 u;
        u.x = f2bf(v.x); u.y = f2bf(v.y); u.z = f2bf(v.z); u.w = f2bf(v.w);
        ((ushort4*)out)[i] = u;
    }
}

// ---------------- CSR build ----------------
__global__ void hist_k(const int* __restrict__ dst, int* __restrict__ deg, int E) {
    for (int e = blockIdx.x * blockDim.x + threadIdx.x; e < E; e += gridDim.x * blockDim.x)
        atomicAdd(&deg[dst[e]], 1);
}

__global__ __launch_bounds__(1024) void scan_k(const int* __restrict__ deg,
                                               int* __restrict__ row_ptr, int n) {
    __shared__ int part[1024];
    const int tid = threadIdx.x;
    const int chunk = (n + 1023) / 1024;
    const int start = tid * chunk;
    const int end = min(start + chunk, n);
    int s = 0;
    for (int i = start; i < end; ++i) s += deg[i];
    part[tid] = s;
    __syncthreads();
    for (int off = 1; off < 1024; off <<= 1) {
        int v = 0;
        if (tid >= off) v = part[tid - off];
        __syncthreads();
        part[tid] += v;
        __syncthreads();
    }
    int base = (tid == 0) ? 0 : part[tid - 1];
    for (int i = start; i < end; ++i) {
        row_ptr[i] = base;
        base += deg[i];
    }
    if (tid == 1023) row_ptr[n] = part[1023];
}

__global__ void scatter_k(const int* __restrict__ src, const int* __restrict__ dst,
                          const int* __restrict__ row_ptr, int* __restrict__ cursor,
                          int* __restrict__ col, int E) {
    for (int e = blockIdx.x * blockDim.x + threadIdx.x; e < E; e += gridDim.x * blockDim.x) {
        int d = dst[e];
        int r = atomicAdd(&cursor[d], 1);
        col[row_ptr[d] + r] = src[e];
    }
}

// ---------------- mean aggregation (bf16 in / bf16 out, fp32 accumulate) ----
// one block per node; blockDim.x == d
__global__ void aggregate_k(const unsigned short* __restrict__ X, const int* __restrict__ col,
                            const int* __restrict__ rp, unsigned short* __restrict__ out, int d) {
    const int n = blockIdx.x;
    const int s = rp[n], e = rp[n + 1];
    const int t = threadIdx.x;
    float acc = 0.f;
    int j = s;
    for (; j + 1 < e; j += 2) {
        int c0 = col[j], c1 = col[j + 1];
        acc += bf2f(X[(size_t)c0 * d + t]);
        acc += bf2f(X[(size_t)c1 * d + t]);
    }
    if (j < e) acc += bf2f(X[(size_t)col[j] * d + t]);
    float dg = (float)(e - s);
    out[(size_t)n * d + t] = f2bf(acc / fmaxf(dg, 1.0f));
}

// ---------------- dual-input bf16 MFMA GEMM, block tile 64 x 256 ------------
// out[m][n] = relu( sum_k A1[m][k]*W1[n][k] + sum_k A2[m][k]*W2[n][k] + bias[n] )
// 4 waves; wave w owns N-strip [w*64, w*64+64). 16x16x32 bf16 MFMA.
// HEAD=false: store Hout (bf16, [M][256]).  HEAD=true: out[m] = dot(row, hw)+hb.
template <int K, bool HEAD>
__global__ __launch_bounds__(256) void gemm_mfma_k(
    const unsigned short* __restrict__ A1, const unsigned short* __restrict__ W1,
    const unsigned short* __restrict__ A2, const unsigned short* __restrict__ W2,
    const float* __restrict__ bias, unsigned short* __restrict__ Hout,
    const float* __restrict__ hw, const float* __restrict__ hb,
    float* __restrict__ out, int M) {
    // padded rows: 32 bf16 + 8 pad = 40 (80 B, keeps 16B alignment, 2-way-max conflicts)
    __shared__ __align__(16) unsigned short sA[64 * 40];
    __shared__ __align__(16) unsigned short sB[256 * 40];
    __shared__ float head_acc[64];

    const int tid = threadIdx.x;
    const int wave = tid >> 6;
    const int lane = tid & 63;
    const int c = lane & 15;        // col within 16x16 tile
    const int q = lane >> 4;        // quad
    const int m0 = blockIdx.x * 64;

    if (HEAD && tid < 64) head_acc[tid] = 0.f;   // covered by first __syncthreads

    floatx4 acc[4][4];
#pragma unroll
    for (int mi = 0; mi < 4; ++mi)
#pragma unroll
        for (int ni = 0; ni < 4; ++ni) acc[mi][ni] = (floatx4){0.f, 0.f, 0.f, 0.f};

    const int arow = tid >> 2;          // 0..63
    const int aseg = (tid & 3) * 8;     // bf16 offset within 32-k chunk
    int gr = m0 + arow;
    if (gr >= M) gr = M - 1;            // clamp; stores guarded

    for (int phase = 0; phase < 2; ++phase) {
        const unsigned short* Ap = phase ? A2 : A1;
        const unsigned short* Wp = phase ? W2 : W1;
        for (int k0 = 0; k0 < K; k0 += 32) {
            short8 va = *(const short8*)(Ap + (size_t)gr * K + k0 + aseg);
            short8 vb[4];
#pragma unroll
            for (int i = 0; i < 4; ++i) {
                int brow = (tid >> 2) + i * 64;
                vb[i] = *(const short8*)(Wp + (size_t)brow * K + k0 + aseg);
            }
            __syncthreads();   // previous iteration's LDS reads done
            *(short8*)&sA[arow * 40 + aseg] = va;
#pragma unroll
            for (int i = 0; i < 4; ++i)
                *(short8*)&sB[((tid >> 2) + i * 64) * 40 + aseg] = vb[i];
            __syncthreads();

            short8 af[4], bf[4];
#pragma unroll
            for (int mi = 0; mi < 4; ++mi)
                af[mi] = *(const short8*)&sA[(mi * 16 + c) * 40 + q * 8];
#pragma unroll
            for (int ni = 0; ni < 4; ++ni)
                bf[ni] = *(const short8*)&sB[(wave * 64 + ni * 16 + c) * 40 + q * 8];
#pragma unroll
            for (int mi = 0; mi < 4; ++mi)
#pragma unroll
                for (int ni = 0; ni < 4; ++ni)
                    acc[mi][ni] = __builtin_amdgcn_mfma_f32_16x16x32_bf16(
                        af[mi], bf[ni], acc[mi][ni], 0, 0, 0);
        }
    }

    if (!HEAD) {
#pragma unroll
        for (int mi = 0; mi < 4; ++mi)
#pragma unroll
            for (int ni = 0; ni < 4; ++ni) {
                const int n = wave * 64 + ni * 16 + c;
                const float bv = bias[n];
#pragma unroll
                for (int reg = 0; reg < 4; ++reg) {
                    const int m = m0 + mi * 16 + q * 4 + reg;
                    if (m < M) {
                        float v = fmaxf(acc[mi][ni][reg] + bv, 0.f);
                        Hout[(size_t)m * 256 + n] = f2bf(v);
                    }
                }
            }
    } else {
#pragma unroll
        for (int mi = 0; mi < 4; ++mi) {
            float p[4] = {0.f, 0.f, 0.f, 0.f};
#pragma unroll
            for (int ni = 0; ni < 4; ++ni) {
                const int n = wave * 64 + ni * 16 + c;
                const float bv = bias[n];
                const float hv = hw[n];
#pragma unroll
                for (int reg = 0; reg < 4; ++reg)
                    p[reg] += fmaxf(acc[mi][ni][reg] + bv, 0.f) * hv;
            }
#pragma unroll
            for (int reg = 0; reg < 4; ++reg) {
                float v = p[reg];
                v += __shfl_xor(v, 1, 64);
                v += __shfl_xor(v, 2, 64);
                v += __shfl_xor(v, 4, 64);
                v += __shfl_xor(v, 8, 64);
                if (c == 0) atomicAdd(&head_acc[mi * 16 + q * 4 + reg], v);
            }
        }
        __syncthreads();
        if (tid < 64) {
            const int m = m0 + tid;
            if (m < M) out[m] = head_acc[tid] + hb[0];
        }
    }
}

// ---------------- launch ----------------
extern "C" void kernel_launch(void* const* d_in, const int* in_sizes, int n_in,
                              void* d_out, int out_size, void* d_ws, size_t ws_size,
                              hipStream_t stream) {
    const float* x    = (const float*)d_in[0];
    const int*   ei   = (const int*)d_in[1];
    const float* W1l  = (const float*)d_in[2];
    const float* b1   = (const float*)d_in[3];
    const float* W1r  = (const float*)d_in[4];
    const float* W2l  = (const float*)d_in[5];
    const float* b2   = (const float*)d_in[6];
    const float* W2r  = (const float*)d_in[7];
    const float* hw   = (const float*)d_in[8];
    const float* hb   = (const float*)d_in[9];
    float* out = (float*)d_out;

    const int M = in_sizes[0] / D_IN;       // 50000
    const int E = in_sizes[1] / 2;          // 800000
    const int* src = ei;
    const int* dst = ei + E;

    size_t off = 0;
    auto alloc = [&](size_t bytes) -> void* {
        void* p = (char*)d_ws + off;
        off += (bytes + 255) & ~(size_t)255;
        return p;
    };
    int* deg    = (int*)alloc((size_t)M * 4);
    int* rp     = (int*)alloc((size_t)(M + 1) * 4);
    int* cursor = (int*)alloc((size_t)M * 4);
    int* col    = (int*)alloc((size_t)E * 4);
    unsigned short* xb    = (unsigned short*)alloc((size_t)M * D_IN * 2);
    unsigned short* w1lb  = (unsigned short*)alloc((size_t)D_H * D_IN * 2);
    unsigned short* w1rb  = (unsigned short*)alloc((size_t)D_H * D_IN * 2);
    unsigned short* w2lb  = (unsigned short*)alloc((size_t)D_H * D_H * 2);
    unsigned short* w2rb  = (unsigned short*)alloc((size_t)D_H * D_H * 2);
    unsigned short* mean1 = (unsigned short*)alloc((size_t)M * D_IN * 2);
    unsigned short* h1    = (unsigned short*)alloc((size_t)M * D_H * 2);
    unsigned short* mean2 = (unsigned short*)alloc((size_t)M * D_H * 2);

    hipMemsetAsync(deg, 0, (size_t)M * 4, stream);
    hipMemsetAsync(cursor, 0, (size_t)M * 4, stream);

    // CSR
    hist_k<<<512, 256, 0, stream>>>(dst, deg, E);
    scan_k<<<1, 1024, 0, stream>>>(deg, rp, M);
    scatter_k<<<512, 256, 0, stream>>>(src, dst, rp, cursor, col, E);

    // bf16 conversions
    auto conv = [&](const float* in, unsigned short* outp, int n) {
        int n4 = n / 4;
        f2bf_k<<<(n4 + 255) / 256, 256, 0, stream>>>(in, outp, n4);
    };
    conv(x, xb, M * D_IN);
    conv(W1l, w1lb, D_H * D_IN);
    conv(W1r, w1rb, D_H * D_IN);
    conv(W2l, w2lb, D_H * D_H);
    conv(W2r, w2rb, D_H * D_H);

    const int nblk = (M + 63) / 64;

    // layer 1
    aggregate_k<<<M, D_IN, 0, stream>>>(xb, col, rp, mean1, D_IN);
    gemm_mfma_k<D_IN, false><<<nblk, 256, 0, stream>>>(
        mean1, w1lb, xb, w1rb, b1, h1, nullptr, nullptr, nullptr, M);

    // layer 2 + fused head
    aggregate_k<<<M, D_H, 0, stream>>>(h1, col, rp, mean2, D_H);
    gemm_mfma_k<D_H, true><<<nblk, 256, 0, stream>>>(
        mean2, w2lb, h1, w2rb, b2, nullptr, hw, hb, out, M);
}

// Round 3
// 409.305 us; speedup vs baseline: 1.7234x; 1.1547x over previous
//
#include <hip/hip_runtime.h>
#include <hip/hip_bf16.h>

#define D_IN 128
#define D_H  256

typedef __attribute__((ext_vector_type(8))) short short8;   // 8 bf16 (4 VGPRs)
typedef __attribute__((ext_vector_type(4))) float floatx4;  // MFMA C/D frag

__device__ __forceinline__ unsigned short f2bf(float f) {
    __hip_bfloat16 h = __float2bfloat16(f);
    return *reinterpret_cast<unsigned short*>(&h);
}
__device__ __forceinline__ float bf2f(unsigned short s) {
    union { unsigned int u; float f; } v;
    v.u = ((unsigned int)s) << 16;
    return v.f;
}

// ---------------- fp32 -> bf16 convert (n multiple of 4) ----------------
__global__ void f2bf_k(const float* __restrict__ in, unsigned short* __restrict__ out, int n4) {
    int i = blockIdx.x * blockDim.x + threadIdx.x;
    if (i < n4) {
        float4 v = ((const float4*)in)[i];
        ushort4 u;
        u.x = f2bf(v.x); u.y = f2bf(v.y); u.z = f2bf(v.z); u.w = f2bf(v.w);
        ((ushort4*)out)[i] = u;
    }
}

// ---------------- CSR build ----------------
__global__ void hist_k(const int* __restrict__ dst, int* __restrict__ deg, int E) {
    for (int e = blockIdx.x * blockDim.x + threadIdx.x; e < E; e += gridDim.x * blockDim.x)
        atomicAdd(&deg[dst[e]], 1);
}

__global__ __launch_bounds__(1024) void scan_k(const int* __restrict__ deg,
                                               int* __restrict__ row_ptr, int n) {
    __shared__ int part[1024];
    const int tid = threadIdx.x;
    const int chunk = (n + 1023) / 1024;
    const int start = tid * chunk;
    const int end = min(start + chunk, n);
    int s = 0;
    for (int i = start; i < end; ++i) s += deg[i];
    part[tid] = s;
    __syncthreads();
    for (int off = 1; off < 1024; off <<= 1) {
        int v = 0;
        if (tid >= off) v = part[tid - off];
        __syncthreads();
        part[tid] += v;
        __syncthreads();
    }
    int base = (tid == 0) ? 0 : part[tid - 1];
    for (int i = start; i < end; ++i) {
        row_ptr[i] = base;
        base += deg[i];
    }
    if (tid == 1023) row_ptr[n] = part[1023];
}

__global__ void scatter_k(const int* __restrict__ src, const int* __restrict__ dst,
                          const int* __restrict__ row_ptr, int* __restrict__ cursor,
                          int* __restrict__ col, int E) {
    for (int e = blockIdx.x * blockDim.x + threadIdx.x; e < E; e += gridDim.x * blockDim.x) {
        int d = dst[e];
        int r = atomicAdd(&cursor[d], 1);
        col[row_ptr[d] + r] = src[e];
    }
}

// ---------------- mean aggregation v2: wave-per-node, vectorized ----------
// D=128: lane loads ushort2 (4B), 8-way neighbor unroll.
// D=256: lane loads ushort4 (8B), 4-way neighbor unroll.
template <int D>
__global__ __launch_bounds__(256) void aggregate_v2(
    const unsigned short* __restrict__ X, const int* __restrict__ col,
    const int* __restrict__ rp, unsigned short* __restrict__ out, int Mnodes) {
    const int node = (blockIdx.x << 2) + (threadIdx.x >> 6);
    if (node >= Mnodes) return;
    const int lane = threadIdx.x & 63;
    const int s = rp[node], e = rp[node + 1];
    constexpr int V = D / 64;                 // ushorts per lane (2 or 4)
    constexpr int UN = (V == 2) ? 8 : 4;      // neighbor unroll

    float acc[V];
#pragma unroll
    for (int v = 0; v < V; ++v) acc[v] = 0.f;

    int j = s;
    for (; j + UN <= e; j += UN) {
        int cs[UN];
#pragma unroll
        for (int u = 0; u < UN; ++u) cs[u] = col[j + u];
        if constexpr (V == 2) {
            unsigned int vals[UN];
#pragma unroll
            for (int u = 0; u < UN; ++u)
                vals[u] = *(const unsigned int*)(X + (size_t)cs[u] * D + lane * 2);
#pragma unroll
            for (int u = 0; u < UN; ++u) {
                acc[0] += bf2f((unsigned short)(vals[u] & 0xffff));
                acc[1] += bf2f((unsigned short)(vals[u] >> 16));
            }
        } else {
            ushort4 vals[UN];
#pragma unroll
            for (int u = 0; u < UN; ++u)
                vals[u] = *(const ushort4*)(X + (size_t)cs[u] * D + lane * 4);
#pragma unroll
            for (int u = 0; u < UN; ++u) {
                acc[0] += bf2f(vals[u].x);
                acc[1] += bf2f(vals[u].y);
                acc[2] += bf2f(vals[u].z);
                acc[3] += bf2f(vals[u].w);
            }
        }
    }
    for (; j < e; ++j) {
        int c0 = col[j];
        if constexpr (V == 2) {
            unsigned int v = *(const unsigned int*)(X + (size_t)c0 * D + lane * 2);
            acc[0] += bf2f((unsigned short)(v & 0xffff));
            acc[1] += bf2f((unsigned short)(v >> 16));
        } else {
            ushort4 v = *(const ushort4*)(X + (size_t)c0 * D + lane * 4);
            acc[0] += bf2f(v.x); acc[1] += bf2f(v.y);
            acc[2] += bf2f(v.z); acc[3] += bf2f(v.w);
        }
    }

    const float inv = 1.f / fmaxf((float)(e - s), 1.f);
    if constexpr (V == 2) {
        ushort2 o;
        o.x = f2bf(acc[0] * inv); o.y = f2bf(acc[1] * inv);
        *(ushort2*)(out + (size_t)node * D + lane * 2) = o;
    } else {
        ushort4 o;
        o.x = f2bf(acc[0] * inv); o.y = f2bf(acc[1] * inv);
        o.z = f2bf(acc[2] * inv); o.w = f2bf(acc[3] * inv);
        *(ushort4*)(out + (size_t)node * D + lane * 4) = o;
    }
}

// ---------------- dual-input bf16 MFMA GEMM, block tile 64 x 256 ------------
// out[m][n] = relu( sum_k A1[m][k]*W1[n][k] + sum_k A2[m][k]*W2[n][k] + bias[n] )
// 4 waves; wave w owns N-strip [w*64, w*64+64). 16x16x32 bf16 MFMA.
// HEAD=false: store Hout (bf16, [M][256]).  HEAD=true: out[m] = dot(row, hw)+hb.
template <int K, bool HEAD>
__global__ __launch_bounds__(256) void gemm_mfma_k(
    const unsigned short* __restrict__ A1, const unsigned short* __restrict__ W1,
    const unsigned short* __restrict__ A2, const unsigned short* __restrict__ W2,
    const float* __restrict__ bias, unsigned short* __restrict__ Hout,
    const float* __restrict__ hw, const float* __restrict__ hb,
    float* __restrict__ out, int M) {
    __shared__ __align__(16) unsigned short sA[64 * 40];
    __shared__ __align__(16) unsigned short sB[256 * 40];
    __shared__ float head_acc[64];

    const int tid = threadIdx.x;
    const int wave = tid >> 6;
    const int lane = tid & 63;
    const int c = lane & 15;        // col within 16x16 tile
    const int q = lane >> 4;        // quad
    const int m0 = blockIdx.x * 64;

    if (HEAD && tid < 64) head_acc[tid] = 0.f;   // covered by first __syncthreads

    floatx4 acc[4][4];
#pragma unroll
    for (int mi = 0; mi < 4; ++mi)
#pragma unroll
        for (int ni = 0; ni < 4; ++ni) acc[mi][ni] = (floatx4){0.f, 0.f, 0.f, 0.f};

    const int arow = tid >> 2;          // 0..63
    const int aseg = (tid & 3) * 8;     // bf16 offset within 32-k chunk
    int gr = m0 + arow;
    if (gr >= M) gr = M - 1;            // clamp; stores guarded

    for (int phase = 0; phase < 2; ++phase) {
        const unsigned short* Ap = phase ? A2 : A1;
        const unsigned short* Wp = phase ? W2 : W1;
        for (int k0 = 0; k0 < K; k0 += 32) {
            short8 va = *(const short8*)(Ap + (size_t)gr * K + k0 + aseg);
            short8 vb[4];
#pragma unroll
            for (int i = 0; i < 4; ++i) {
                int brow = (tid >> 2) + i * 64;
                vb[i] = *(const short8*)(Wp + (size_t)brow * K + k0 + aseg);
            }
            __syncthreads();   // previous iteration's LDS reads done
            *(short8*)&sA[arow * 40 + aseg] = va;
#pragma unroll
            for (int i = 0; i < 4; ++i)
                *(short8*)&sB[((tid >> 2) + i * 64) * 40 + aseg] = vb[i];
            __syncthreads();

            short8 af[4], bf[4];
#pragma unroll
            for (int mi = 0; mi < 4; ++mi)
                af[mi] = *(const short8*)&sA[(mi * 16 + c) * 40 + q * 8];
#pragma unroll
            for (int ni = 0; ni < 4; ++ni)
                bf[ni] = *(const short8*)&sB[(wave * 64 + ni * 16 + c) * 40 + q * 8];
#pragma unroll
            for (int mi = 0; mi < 4; ++mi)
#pragma unroll
                for (int ni = 0; ni < 4; ++ni)
                    acc[mi][ni] = __builtin_amdgcn_mfma_f32_16x16x32_bf16(
                        af[mi], bf[ni], acc[mi][ni], 0, 0, 0);
        }
    }

    if (!HEAD) {
#pragma unroll
        for (int mi = 0; mi < 4; ++mi)
#pragma unroll
            for (int ni = 0; ni < 4; ++ni) {
                const int n = wave * 64 + ni * 16 + c;
                const float bv = bias[n];
#pragma unroll
                for (int reg = 0; reg < 4; ++reg) {
                    const int m = m0 + mi * 16 + q * 4 + reg;
                    if (m < M) {
                        float v = fmaxf(acc[mi][ni][reg] + bv, 0.f);
                        Hout[(size_t)m * 256 + n] = f2bf(v);
                    }
                }
            }
    } else {
#pragma unroll
        for (int mi = 0; mi < 4; ++mi) {
            float p[4] = {0.f, 0.f, 0.f, 0.f};
#pragma unroll
            for (int ni = 0; ni < 4; ++ni) {
                const int n = wave * 64 + ni * 16 + c;
                const float bv = bias[n];
                const float hv = hw[n];
#pragma unroll
                for (int reg = 0; reg < 4; ++reg)
                    p[reg] += fmaxf(acc[mi][ni][reg] + bv, 0.f) * hv;
            }
#pragma unroll
            for (int reg = 0; reg < 4; ++reg) {
                float v = p[reg];
                v += __shfl_xor(v, 1, 64);
                v += __shfl_xor(v, 2, 64);
                v += __shfl_xor(v, 4, 64);
                v += __shfl_xor(v, 8, 64);
                if (c == 0) atomicAdd(&head_acc[mi * 16 + q * 4 + reg], v);
            }
        }
        __syncthreads();
        if (tid < 64) {
            const int m = m0 + tid;
            if (m < M) out[m] = head_acc[tid] + hb[0];
        }
    }
}

// ---------------- launch ----------------
extern "C" void kernel_launch(void* const* d_in, const int* in_sizes, int n_in,
                              void* d_out, int out_size, void* d_ws, size_t ws_size,
                              hipStream_t stream) {
    const float* x    = (const float*)d_in[0];
    const int*   ei   = (const int*)d_in[1];
    const float* W1l  = (const float*)d_in[2];
    const float* b1   = (const float*)d_in[3];
    const float* W1r  = (const float*)d_in[4];
    const float* W2l  = (const float*)d_in[5];
    const float* b2   = (const float*)d_in[6];
    const float* W2r  = (const float*)d_in[7];
    const float* hw   = (const float*)d_in[8];
    const float* hb   = (const float*)d_in[9];
    float* out = (float*)d_out;

    const int M = in_sizes[0] / D_IN;       // 50000
    const int E = in_sizes[1] / 2;          // 800000
    const int* src = ei;
    const int* dst = ei + E;

    size_t off = 0;
    auto alloc = [&](size_t bytes) -> void* {
        void* p = (char*)d_ws + off;
        off += (bytes + 255) & ~(size_t)255;
        return p;
    };
    int* deg    = (int*)alloc((size_t)M * 4);
    int* rp     = (int*)alloc((size_t)(M + 1) * 4);
    int* cursor = (int*)alloc((size_t)M * 4);
    int* col    = (int*)alloc((size_t)E * 4);
    unsigned short* xb    = (unsigned short*)alloc((size_t)M * D_IN * 2);
    unsigned short* w1lb  = (unsigned short*)alloc((size_t)D_H * D_IN * 2);
    unsigned short* w1rb  = (unsigned short*)alloc((size_t)D_H * D_IN * 2);
    unsigned short* w2lb  = (unsigned short*)alloc((size_t)D_H * D_H * 2);
    unsigned short* w2rb  = (unsigned short*)alloc((size_t)D_H * D_H * 2);
    unsigned short* mean1 = (unsigned short*)alloc((size_t)M * D_IN * 2);
    unsigned short* h1    = (unsigned short*)alloc((size_t)M * D_H * 2);
    unsigned short* mean2 = (unsigned short*)alloc((size_t)M * D_H * 2);

    hipMemsetAsync(deg, 0, (size_t)M * 4, stream);
    hipMemsetAsync(cursor, 0, (size_t)M * 4, stream);

    // CSR
    hist_k<<<512, 256, 0, stream>>>(dst, deg, E);
    scan_k<<<1, 1024, 0, stream>>>(deg, rp, M);
    scatter_k<<<512, 256, 0, stream>>>(src, dst, rp, cursor, col, E);

    // bf16 conversions
    auto conv = [&](const float* in, unsigned short* outp, int n) {
        int n4 = n / 4;
        f2bf_k<<<(n4 + 255) / 256, 256, 0, stream>>>(in, outp, n4);
    };
    conv(x, xb, M * D_IN);
    conv(W1l, w1lb, D_H * D_IN);
    conv(W1r, w1rb, D_H * D_IN);
    conv(W2l, w2lb, D_H * D_H);
    conv(W2r, w2rb, D_H * D_H);

    const int nblk = (M + 63) / 64;
    const int ablk = (M + 3) / 4;

    // layer 1
    aggregate_v2<D_IN><<<ablk, 256, 0, stream>>>(xb, col, rp, mean1, M);
    gemm_mfma_k<D_IN, false><<<nblk, 256, 0, stream>>>(
        mean1, w1lb, xb, w1rb, b1, h1, nullptr, nullptr, nullptr, M);

    // layer 2 + fused head
    aggregate_v2<D_H><<<ablk, 256, 0, stream>>>(h1, col, rp, mean2, M);
    gemm_mfma_k<D_H, true><<<nblk, 256, 0, stream>>>(
        mean2, w2lb, h1, w2rb, b2, nullptr, hw, hb, out, M);
}

// Round 4
// 338.694 us; speedup vs baseline: 2.0827x; 1.2085x over previous
//
#include <hip/hip_runtime.h>
#include <hip/hip_bf16.h>

#define D_IN 128
#define D_H  256

typedef __attribute__((ext_vector_type(8))) short short8;   // 8 bf16 (4 VGPRs)
typedef __attribute__((ext_vector_type(4))) float floatx4;  // MFMA C/D frag

__device__ __forceinline__ unsigned short f2bf(float f) {
    __hip_bfloat16 h = __float2bfloat16(f);
    return *reinterpret_cast<unsigned short*>(&h);
}
__device__ __forceinline__ float bf2f(unsigned short s) {
    union { unsigned int u; float f; } v;
    v.u = ((unsigned int)s) << 16;
    return v.f;
}

// ---------------- fp32 -> bf16 convert (n multiple of 4) ----------------
__global__ void f2bf_k(const float* __restrict__ in, unsigned short* __restrict__ out, int n4) {
    int i = blockIdx.x * blockDim.x + threadIdx.x;
    if (i < n4) {
        float4 v = ((const float4*)in)[i];
        ushort4 u;
        u.x = f2bf(v.x); u.y = f2bf(v.y); u.z = f2bf(v.z); u.w = f2bf(v.w);
        ((ushort4*)out)[i] = u;
    }
}

// ---------------- CSR build ----------------
__global__ void hist_k(const int* __restrict__ dst, int* __restrict__ deg, int E) {
    for (int e = blockIdx.x * blockDim.x + threadIdx.x; e < E; e += gridDim.x * blockDim.x)
        atomicAdd(&deg[dst[e]], 1);
}

// --- 3-phase device-wide exclusive scan (segments of 2048) ---
__global__ __launch_bounds__(256) void scan_part_k(const int* __restrict__ deg,
                                                   int* __restrict__ bsum, int n) {
    const int b = blockIdx.x, tid = threadIdx.x;
    const int base = b * 2048;
    const int lim = min(base + 2048, n);
    int s = 0;
    for (int i = base + tid; i < lim; i += 256) s += deg[i];
    __shared__ int red[256];
    red[tid] = s; __syncthreads();
    for (int off = 128; off > 0; off >>= 1) {
        if (tid < off) red[tid] += red[tid + off];
        __syncthreads();
    }
    if (tid == 0) bsum[b] = red[0];
}

__global__ __launch_bounds__(256) void scan_bsum_k(int* __restrict__ bsum, int nb) {
    __shared__ int buf[256];
    const int tid = threadIdx.x;
    buf[tid] = (tid < nb) ? bsum[tid] : 0;
    __syncthreads();
    for (int off = 1; off < 256; off <<= 1) {
        int v = (tid >= off) ? buf[tid - off] : 0;
        __syncthreads();
        buf[tid] += v;
        __syncthreads();
    }
    if (tid < nb) bsum[tid] = (tid == 0) ? 0 : buf[tid - 1];
}

__global__ __launch_bounds__(256) void scan_final_k(const int* __restrict__ deg,
                                                    const int* __restrict__ bsum,
                                                    int* __restrict__ row_ptr,
                                                    int n, int E) {
    const int b = blockIdx.x, tid = threadIdx.x;
    const int base = b * 2048;
    __shared__ int buf[2048];
    __shared__ int ts[256];
    for (int i = tid; i < 2048; i += 256)
        buf[i] = (base + i < n) ? deg[base + i] : 0;
    __syncthreads();
    int local[8];
    int s = 0;
#pragma unroll
    for (int j = 0; j < 8; ++j) { local[j] = s; s += buf[tid * 8 + j]; }
    ts[tid] = s; __syncthreads();
    for (int off = 1; off < 256; off <<= 1) {
        int v = (tid >= off) ? ts[tid - off] : 0;
        __syncthreads();
        ts[tid] += v;
        __syncthreads();
    }
    const int prefix = bsum[b] + ((tid == 0) ? 0 : ts[tid - 1]);
#pragma unroll
    for (int j = 0; j < 8; ++j) {
        int idx = base + tid * 8 + j;
        if (idx < n) row_ptr[idx] = prefix + local[j];
    }
    if (b == 0 && tid == 0) row_ptr[n] = E;
}

__global__ void scatter_k(const int* __restrict__ src, const int* __restrict__ dst,
                          const int* __restrict__ row_ptr, int* __restrict__ cursor,
                          int* __restrict__ col, int E) {
    for (int e = blockIdx.x * blockDim.x + threadIdx.x; e < E; e += gridDim.x * blockDim.x) {
        int d = dst[e];
        int r = atomicAdd(&cursor[d], 1);
        col[row_ptr[d] + r] = src[e];
    }
}

// ---------------- mean aggregation v2: wave-per-node, vectorized ----------
template <int D>
__global__ __launch_bounds__(256) void aggregate_v2(
    const unsigned short* __restrict__ X, const int* __restrict__ col,
    const int* __restrict__ rp, unsigned short* __restrict__ out, int Mnodes) {
    const int node = (blockIdx.x << 2) + (threadIdx.x >> 6);
    if (node >= Mnodes) return;
    const int lane = threadIdx.x & 63;
    const int s = rp[node], e = rp[node + 1];
    constexpr int V = D / 64;                 // ushorts per lane (2 or 4)
    constexpr int UN = (V == 2) ? 8 : 4;      // neighbor unroll

    float acc[V];
#pragma unroll
    for (int v = 0; v < V; ++v) acc[v] = 0.f;

    int j = s;
    for (; j + UN <= e; j += UN) {
        int cs[UN];
#pragma unroll
        for (int u = 0; u < UN; ++u) cs[u] = col[j + u];
        if constexpr (V == 2) {
            unsigned int vals[UN];
#pragma unroll
            for (int u = 0; u < UN; ++u)
                vals[u] = *(const unsigned int*)(X + (size_t)cs[u] * D + lane * 2);
#pragma unroll
            for (int u = 0; u < UN; ++u) {
                acc[0] += bf2f((unsigned short)(vals[u] & 0xffff));
                acc[1] += bf2f((unsigned short)(vals[u] >> 16));
            }
        } else {
            ushort4 vals[UN];
#pragma unroll
            for (int u = 0; u < UN; ++u)
                vals[u] = *(const ushort4*)(X + (size_t)cs[u] * D + lane * 4);
#pragma unroll
            for (int u = 0; u < UN; ++u) {
                acc[0] += bf2f(vals[u].x);
                acc[1] += bf2f(vals[u].y);
                acc[2] += bf2f(vals[u].z);
                acc[3] += bf2f(vals[u].w);
            }
        }
    }
    for (; j < e; ++j) {
        int c0 = col[j];
        if constexpr (V == 2) {
            unsigned int v = *(const unsigned int*)(X + (size_t)c0 * D + lane * 2);
            acc[0] += bf2f((unsigned short)(v & 0xffff));
            acc[1] += bf2f((unsigned short)(v >> 16));
        } else {
            ushort4 v = *(const ushort4*)(X + (size_t)c0 * D + lane * 4);
            acc[0] += bf2f(v.x); acc[1] += bf2f(v.y);
            acc[2] += bf2f(v.z); acc[3] += bf2f(v.w);
        }
    }

    const float inv = 1.f / fmaxf((float)(e - s), 1.f);
    if constexpr (V == 2) {
        ushort2 o;
        o.x = f2bf(acc[0] * inv); o.y = f2bf(acc[1] * inv);
        *(ushort2*)(out + (size_t)node * D + lane * 2) = o;
    } else {
        ushort4 o;
        o.x = f2bf(acc[0] * inv); o.y = f2bf(acc[1] * inv);
        o.z = f2bf(acc[2] * inv); o.w = f2bf(acc[3] * inv);
        *(ushort4*)(out + (size_t)node * D + lane * 4) = o;
    }
}

// ---------------- dual-input bf16 MFMA GEMM, block tile 64 x 256 ------------
template <int K, bool HEAD>
__global__ __launch_bounds__(256) void gemm_mfma_k(
    const unsigned short* __restrict__ A1, const unsigned short* __restrict__ W1,
    const unsigned short* __restrict__ A2, const unsigned short* __restrict__ W2,
    const float* __restrict__ bias, unsigned short* __restrict__ Hout,
    const float* __restrict__ hw, const float* __restrict__ hb,
    float* __restrict__ out, int M) {
    __shared__ __align__(16) unsigned short sA[64 * 40];
    __shared__ __align__(16) unsigned short sB[256 * 40];
    __shared__ float head_acc[64];

    const int tid = threadIdx.x;
    const int wave = tid >> 6;
    const int lane = tid & 63;
    const int c = lane & 15;        // col within 16x16 tile
    const int q = lane >> 4;        // quad
    const int m0 = blockIdx.x * 64;

    if (HEAD && tid < 64) head_acc[tid] = 0.f;   // covered by first __syncthreads

    floatx4 acc[4][4];
#pragma unroll
    for (int mi = 0; mi < 4; ++mi)
#pragma unroll
        for (int ni = 0; ni < 4; ++ni) acc[mi][ni] = (floatx4){0.f, 0.f, 0.f, 0.f};

    const int arow = tid >> 2;          // 0..63
    const int aseg = (tid & 3) * 8;     // bf16 offset within 32-k chunk
    int gr = m0 + arow;
    if (gr >= M) gr = M - 1;            // clamp; stores guarded

    for (int phase = 0; phase < 2; ++phase) {
        const unsigned short* Ap = phase ? A2 : A1;
        const unsigned short* Wp = phase ? W2 : W1;
        for (int k0 = 0; k0 < K; k0 += 32) {
            short8 va = *(const short8*)(Ap + (size_t)gr * K + k0 + aseg);
            short8 vb[4];
#pragma unroll
            for (int i = 0; i < 4; ++i) {
                int brow = (tid >> 2) + i * 64;
                vb[i] = *(const short8*)(Wp + (size_t)brow * K + k0 + aseg);
            }
            __syncthreads();   // previous iteration's LDS reads done
            *(short8*)&sA[arow * 40 + aseg] = va;
#pragma unroll
            for (int i = 0; i < 4; ++i)
                *(short8*)&sB[((tid >> 2) + i * 64) * 40 + aseg] = vb[i];
            __syncthreads();

            short8 af[4], bf[4];
#pragma unroll
            for (int mi = 0; mi < 4; ++mi)
                af[mi] = *(const short8*)&sA[(mi * 16 + c) * 40 + q * 8];
#pragma unroll
            for (int ni = 0; ni < 4; ++ni)
                bf[ni] = *(const short8*)&sB[(wave * 64 + ni * 16 + c) * 40 + q * 8];
#pragma unroll
            for (int mi = 0; mi < 4; ++mi)
#pragma unroll
                for (int ni = 0; ni < 4; ++ni)
                    acc[mi][ni] = __builtin_amdgcn_mfma_f32_16x16x32_bf16(
                        af[mi], bf[ni], acc[mi][ni], 0, 0, 0);
        }
    }

    if (!HEAD) {
#pragma unroll
        for (int mi = 0; mi < 4; ++mi)
#pragma unroll
            for (int ni = 0; ni < 4; ++ni) {
                const int n = wave * 64 + ni * 16 + c;
                const float bv = bias[n];
#pragma unroll
                for (int reg = 0; reg < 4; ++reg) {
                    const int m = m0 + mi * 16 + q * 4 + reg;
                    if (m < M) {
                        float v = fmaxf(acc[mi][ni][reg] + bv, 0.f);
                        Hout[(size_t)m * 256 + n] = f2bf(v);
                    }
                }
            }
    } else {
#pragma unroll
        for (int mi = 0; mi < 4; ++mi) {
            float p[4] = {0.f, 0.f, 0.f, 0.f};
#pragma unroll
            for (int ni = 0; ni < 4; ++ni) {
                const int n = wave * 64 + ni * 16 + c;
                const float bv = bias[n];
                const float hv = hw[n];
#pragma unroll
                for (int reg = 0; reg < 4; ++reg)
                    p[reg] += fmaxf(acc[mi][ni][reg] + bv, 0.f) * hv;
            }
#pragma unroll
            for (int reg = 0; reg < 4; ++reg) {
                float v = p[reg];
                v += __shfl_xor(v, 1, 64);
                v += __shfl_xor(v, 2, 64);
                v += __shfl_xor(v, 4, 64);
                v += __shfl_xor(v, 8, 64);
                if (c == 0) atomicAdd(&head_acc[mi * 16 + q * 4 + reg], v);
            }
        }
        __syncthreads();
        if (tid < 64) {
            const int m = m0 + tid;
            if (m < M) out[m] = head_acc[tid] + hb[0];
        }
    }
}

// ---------------- launch ----------------
extern "C" void kernel_launch(void* const* d_in, const int* in_sizes, int n_in,
                              void* d_out, int out_size, void* d_ws, size_t ws_size,
                              hipStream_t stream) {
    const float* x    = (const float*)d_in[0];
    const int*   ei   = (const int*)d_in[1];
    const float* W1l  = (const float*)d_in[2];
    const float* b1   = (const float*)d_in[3];
    const float* W1r  = (const float*)d_in[4];
    const float* W2l  = (const float*)d_in[5];
    const float* b2   = (const float*)d_in[6];
    const float* W2r  = (const float*)d_in[7];
    const float* hw   = (const float*)d_in[8];
    const float* hb   = (const float*)d_in[9];
    float* out = (float*)d_out;

    const int M = in_sizes[0] / D_IN;       // 50000
    const int E = in_sizes[1] / 2;          // 800000
    const int* src = ei;
    const int* dst = ei + E;

    size_t off = 0;
    auto alloc = [&](size_t bytes) -> void* {
        void* p = (char*)d_ws + off;
        off += (bytes + 255) & ~(size_t)255;
        return p;
    };
    int* deg    = (int*)alloc((size_t)M * 4);
    int* rp     = (int*)alloc((size_t)(M + 1) * 4);
    int* cursor = (int*)alloc((size_t)M * 4);
    int* bsum   = (int*)alloc(256 * 4);
    int* col    = (int*)alloc((size_t)E * 4);
    unsigned short* xb    = (unsigned short*)alloc((size_t)M * D_IN * 2);
    unsigned short* w1lb  = (unsigned short*)alloc((size_t)D_H * D_IN * 2);
    unsigned short* w1rb  = (unsigned short*)alloc((size_t)D_H * D_IN * 2);
    unsigned short* w2lb  = (unsigned short*)alloc((size_t)D_H * D_H * 2);
    unsigned short* w2rb  = (unsigned short*)alloc((size_t)D_H * D_H * 2);
    unsigned short* mean1 = (unsigned short*)alloc((size_t)M * D_IN * 2);
    unsigned short* h1    = (unsigned short*)alloc((size_t)M * D_H * 2);
    unsigned short* mean2 = (unsigned short*)alloc((size_t)M * D_H * 2);

    hipMemsetAsync(deg, 0, (size_t)M * 4, stream);
    hipMemsetAsync(cursor, 0, (size_t)M * 4, stream);

    // CSR
    const int nseg = (M + 2047) / 2048;     // 25
    hist_k<<<512, 256, 0, stream>>>(dst, deg, E);
    scan_part_k<<<nseg, 256, 0, stream>>>(deg, bsum, M);
    scan_bsum_k<<<1, 256, 0, stream>>>(bsum, nseg);
    scan_final_k<<<nseg, 256, 0, stream>>>(deg, bsum, rp, M, E);
    scatter_k<<<512, 256, 0, stream>>>(src, dst, rp, cursor, col, E);

    // bf16 conversions
    auto conv = [&](const float* in, unsigned short* outp, int n) {
        int n4 = n / 4;
        f2bf_k<<<(n4 + 255) / 256, 256, 0, stream>>>(in, outp, n4);
    };
    conv(x, xb, M * D_IN);
    conv(W1l, w1lb, D_H * D_IN);
    conv(W1r, w1rb, D_H * D_IN);
    conv(W2l, w2lb, D_H * D_H);
    conv(W2r, w2rb, D_H * D_H);

    const int nblk = (M + 63) / 64;
    const int ablk = (M + 3) / 4;

    // layer 1
    aggregate_v2<D_IN><<<ablk, 256, 0, stream>>>(xb, col, rp, mean1, M);
    gemm_mfma_k<D_IN, false><<<nblk, 256, 0, stream>>>(
        mean1, w1lb, xb, w1rb, b1, h1, nullptr, nullptr, nullptr, M);

    // layer 2 + fused head
    aggregate_v2<D_H><<<ablk, 256, 0, stream>>>(h1, col, rp, mean2, M);
    gemm_mfma_k<D_H, true><<<nblk, 256, 0, stream>>>(
        mean2, w2lb, h1, w2rb, b2, nullptr, hw, hb, out, M);
}

// Round 5
// 315.273 us; speedup vs baseline: 2.2374x; 1.0743x over previous
//
#include <hip/hip_runtime.h>
#include <hip/hip_bf16.h>

#define D_IN 128
#define D_H  256

typedef __attribute__((ext_vector_type(8))) short short8;   // 8 bf16 (4 VGPRs)
typedef __attribute__((ext_vector_type(4))) float floatx4;  // MFMA C/D frag

__device__ __forceinline__ unsigned short f2bf(float f) {
    __hip_bfloat16 h = __float2bfloat16(f);
    return *reinterpret_cast<unsigned short*>(&h);
}
__device__ __forceinline__ float bf2f(unsigned short s) {
    union { unsigned int u; float f; } v;
    v.u = ((unsigned int)s) << 16;
    return v.f;
}

// ---------------- fused fp32 -> bf16 convert for x + all 4 weights ---------
__global__ void f2bf_all_k(const float* __restrict__ x, unsigned short* __restrict__ xb, int nx4,
                           const float* __restrict__ w1l, unsigned short* __restrict__ w1lb,
                           const float* __restrict__ w1r, unsigned short* __restrict__ w1rb, int nw14,
                           const float* __restrict__ w2l, unsigned short* __restrict__ w2lb,
                           const float* __restrict__ w2r, unsigned short* __restrict__ w2rb, int nw24) {
    int i = blockIdx.x * blockDim.x + threadIdx.x;
    const float* s; unsigned short* d; int k;
    if (i < nx4) { s = x; d = xb; k = i; }
    else {
        i -= nx4;
        if (i < nw14) { s = w1l; d = w1lb; k = i; }
        else {
            i -= nw14;
            if (i < nw14) { s = w1r; d = w1rb; k = i; }
            else {
                i -= nw14;
                if (i < nw24) { s = w2l; d = w2lb; k = i; }
                else {
                    i -= nw24;
                    if (i >= nw24) return;
                    s = w2r; d = w2rb; k = i;
                }
            }
        }
    }
    float4 v = ((const float4*)s)[k];
    ushort4 u;
    u.x = f2bf(v.x); u.y = f2bf(v.y); u.z = f2bf(v.z); u.w = f2bf(v.w);
    ((ushort4*)d)[k] = u;
}

// ---------------- CSR build ----------------
__global__ void hist_k(const int* __restrict__ dst, int* __restrict__ deg, int E) {
    for (int e = blockIdx.x * blockDim.x + threadIdx.x; e < E; e += gridDim.x * blockDim.x)
        atomicAdd(&deg[dst[e]], 1);
}

__global__ __launch_bounds__(256) void scan_part_k(const int* __restrict__ deg,
                                                   int* __restrict__ bsum, int n) {
    const int b = blockIdx.x, tid = threadIdx.x;
    const int base = b * 2048;
    const int lim = min(base + 2048, n);
    int s = 0;
    for (int i = base + tid; i < lim; i += 256) s += deg[i];
    __shared__ int red[256];
    red[tid] = s; __syncthreads();
    for (int off = 128; off > 0; off >>= 1) {
        if (tid < off) red[tid] += red[tid + off];
        __syncthreads();
    }
    if (tid == 0) bsum[b] = red[0];
}

// final phase: each block computes its own prefix over bsum (nb <= 32 entries)
__global__ __launch_bounds__(256) void scan_final_k(const int* __restrict__ deg,
                                                    const int* __restrict__ bsum,
                                                    int* __restrict__ row_ptr,
                                                    int n, int E) {
    const int b = blockIdx.x, tid = threadIdx.x;
    const int base = b * 2048;
    __shared__ int buf[2048];
    __shared__ int ts[256];
    __shared__ int blk_prefix;
    if (tid == 0) {
        int p = 0;
        for (int i = 0; i < b; ++i) p += bsum[i];
        blk_prefix = p;
    }
    for (int i = tid; i < 2048; i += 256)
        buf[i] = (base + i < n) ? deg[base + i] : 0;
    __syncthreads();
    int local[8];
    int s = 0;
#pragma unroll
    for (int j = 0; j < 8; ++j) { local[j] = s; s += buf[tid * 8 + j]; }
    ts[tid] = s; __syncthreads();
    for (int off = 1; off < 256; off <<= 1) {
        int v = (tid >= off) ? ts[tid - off] : 0;
        __syncthreads();
        ts[tid] += v;
        __syncthreads();
    }
    const int prefix = blk_prefix + ((tid == 0) ? 0 : ts[tid - 1]);
#pragma unroll
    for (int j = 0; j < 8; ++j) {
        int idx = base + tid * 8 + j;
        if (idx < n) row_ptr[idx] = prefix + local[j];
    }
    if (b == 0 && tid == 0) row_ptr[n] = E;
}

__global__ void scatter_k(const int* __restrict__ src, const int* __restrict__ dst,
                          const int* __restrict__ row_ptr, int* __restrict__ cursor,
                          int* __restrict__ col, int E) {
    for (int e = blockIdx.x * blockDim.x + threadIdx.x; e < E; e += gridDim.x * blockDim.x) {
        int d = dst[e];
        int r = atomicAdd(&cursor[d], 1);
        col[row_ptr[d] + r] = src[e];
    }
}

// ---------------- mean aggregation v3 ----------
// wave-per-node; node made wave-uniform via readfirstlane so col[] loads are
// scalar (s_load), keeping the VMEM queue free for the row gathers.
template <int D, int UN>
__device__ __forceinline__ int agg_stage(const unsigned short* __restrict__ X,
                                         const int* __restrict__ col,
                                         int j, int e, int lane, float* acc) {
    constexpr int V = D / 64;
    for (; j + UN <= e; j += UN) {
        int cs[UN];
#pragma unroll
        for (int u = 0; u < UN; ++u) cs[u] = col[j + u];
        if constexpr (V == 2) {
            unsigned int vals[UN];
#pragma unroll
            for (int u = 0; u < UN; ++u)
                vals[u] = *(const unsigned int*)(X + (size_t)cs[u] * D + lane * 2);
#pragma unroll
            for (int u = 0; u < UN; ++u) {
                acc[0] += bf2f((unsigned short)(vals[u] & 0xffff));
                acc[1] += bf2f((unsigned short)(vals[u] >> 16));
            }
        } else {
            ushort4 vals[UN];
#pragma unroll
            for (int u = 0; u < UN; ++u)
                vals[u] = *(const ushort4*)(X + (size_t)cs[u] * D + lane * 4);
#pragma unroll
            for (int u = 0; u < UN; ++u) {
                acc[0] += bf2f(vals[u].x); acc[1] += bf2f(vals[u].y);
                acc[2] += bf2f(vals[u].z); acc[3] += bf2f(vals[u].w);
            }
        }
    }
    return j;
}

template <int D>
__global__ __launch_bounds__(256) void aggregate_v3(
    const unsigned short* __restrict__ X, const int* __restrict__ col,
    const int* __restrict__ rp, unsigned short* __restrict__ out, int Mnodes) {
    int node = __builtin_amdgcn_readfirstlane((blockIdx.x << 2) + (threadIdx.x >> 6));
    if (node >= Mnodes) return;
    const int lane = threadIdx.x & 63;
    const int s = rp[node], e = rp[node + 1];
    constexpr int V = D / 64;
    float acc[V] = {0.f};

    int j = s;
    j = agg_stage<D, 8>(X, col, j, e, lane, acc);
    j = agg_stage<D, 4>(X, col, j, e, lane, acc);
    j = agg_stage<D, 2>(X, col, j, e, lane, acc);
    j = agg_stage<D, 1>(X, col, j, e, lane, acc);

    const float inv = 1.f / fmaxf((float)(e - s), 1.f);
    if constexpr (V == 2) {
        ushort2 o;
        o.x = f2bf(acc[0] * inv); o.y = f2bf(acc[1] * inv);
        *(ushort2*)(out + (size_t)node * D + lane * 2) = o;
    } else {
        ushort4 o;
        o.x = f2bf(acc[0] * inv); o.y = f2bf(acc[1] * inv);
        o.z = f2bf(acc[2] * inv); o.w = f2bf(acc[3] * inv);
        *(ushort4*)(out + (size_t)node * D + lane * 4) = o;
    }
}

// ---------------- dual-input bf16 MFMA GEMM, block tile 64 x 256 ------------
template <int K, bool HEAD>
__global__ __launch_bounds__(256) void gemm_mfma_k(
    const unsigned short* __restrict__ A1, const unsigned short* __restrict__ W1,
    const unsigned short* __restrict__ A2, const unsigned short* __restrict__ W2,
    const float* __restrict__ bias, unsigned short* __restrict__ Hout,
    const float* __restrict__ hw, const float* __restrict__ hb,
    float* __restrict__ out, int M) {
    __shared__ __align__(16) unsigned short sA[64 * 40];
    __shared__ __align__(16) unsigned short sB[256 * 40];
    __shared__ float head_acc[64];

    const int tid = threadIdx.x;
    const int wave = tid >> 6;
    const int lane = tid & 63;
    const int c = lane & 15;        // col within 16x16 tile
    const int q = lane >> 4;        // quad
    const int m0 = blockIdx.x * 64;

    if (HEAD && tid < 64) head_acc[tid] = 0.f;   // covered by first __syncthreads

    floatx4 acc[4][4];
#pragma unroll
    for (int mi = 0; mi < 4; ++mi)
#pragma unroll
        for (int ni = 0; ni < 4; ++ni) acc[mi][ni] = (floatx4){0.f, 0.f, 0.f, 0.f};

    const int arow = tid >> 2;          // 0..63
    const int aseg = (tid & 3) * 8;     // bf16 offset within 32-k chunk
    int gr = m0 + arow;
    if (gr >= M) gr = M - 1;            // clamp; stores guarded

    for (int phase = 0; phase < 2; ++phase) {
        const unsigned short* Ap = phase ? A2 : A1;
        const unsigned short* Wp = phase ? W2 : W1;
        for (int k0 = 0; k0 < K; k0 += 32) {
            short8 va = *(const short8*)(Ap + (size_t)gr * K + k0 + aseg);
            short8 vb[4];
#pragma unroll
            for (int i = 0; i < 4; ++i) {
                int brow = (tid >> 2) + i * 64;
                vb[i] = *(const short8*)(Wp + (size_t)brow * K + k0 + aseg);
            }
            __syncthreads();   // previous iteration's LDS reads done
            *(short8*)&sA[arow * 40 + aseg] = va;
#pragma unroll
            for (int i = 0; i < 4; ++i)
                *(short8*)&sB[((tid >> 2) + i * 64) * 40 + aseg] = vb[i];
            __syncthreads();

            short8 af[4], bf[4];
#pragma unroll
            for (int mi = 0; mi < 4; ++mi)
                af[mi] = *(const short8*)&sA[(mi * 16 + c) * 40 + q * 8];
#pragma unroll
            for (int ni = 0; ni < 4; ++ni)
                bf[ni] = *(const short8*)&sB[(wave * 64 + ni * 16 + c) * 40 + q * 8];
#pragma unroll
            for (int mi = 0; mi < 4; ++mi)
#pragma unroll
                for (int ni = 0; ni < 4; ++ni)
                    acc[mi][ni] = __builtin_amdgcn_mfma_f32_16x16x32_bf16(
                        af[mi], bf[ni], acc[mi][ni], 0, 0, 0);
        }
    }

    if (!HEAD) {
#pragma unroll
        for (int mi = 0; mi < 4; ++mi)
#pragma unroll
            for (int ni = 0; ni < 4; ++ni) {
                const int n = wave * 64 + ni * 16 + c;
                const float bv = bias[n];
#pragma unroll
                for (int reg = 0; reg < 4; ++reg) {
                    const int m = m0 + mi * 16 + q * 4 + reg;
                    if (m < M) {
                        float v = fmaxf(acc[mi][ni][reg] + bv, 0.f);
                        Hout[(size_t)m * 256 + n] = f2bf(v);
                    }
                }
            }
    } else {
#pragma unroll
        for (int mi = 0; mi < 4; ++mi) {
            float p[4] = {0.f, 0.f, 0.f, 0.f};
#pragma unroll
            for (int ni = 0; ni < 4; ++ni) {
                const int n = wave * 64 + ni * 16 + c;
                const float bv = bias[n];
                const float hv = hw[n];
#pragma unroll
                for (int reg = 0; reg < 4; ++reg)
                    p[reg] += fmaxf(acc[mi][ni][reg] + bv, 0.f) * hv;
            }
#pragma unroll
            for (int reg = 0; reg < 4; ++reg) {
                float v = p[reg];
                v += __shfl_xor(v, 1, 64);
                v += __shfl_xor(v, 2, 64);
                v += __shfl_xor(v, 4, 64);
                v += __shfl_xor(v, 8, 64);
                if (c == 0) atomicAdd(&head_acc[mi * 16 + q * 4 + reg], v);
            }
        }
        __syncthreads();
        if (tid < 64) {
            const int m = m0 + tid;
            if (m < M) out[m] = head_acc[tid] + hb[0];
        }
    }
}

// ---------------- launch ----------------
extern "C" void kernel_launch(void* const* d_in, const int* in_sizes, int n_in,
                              void* d_out, int out_size, void* d_ws, size_t ws_size,
                              hipStream_t stream) {
    const float* x    = (const float*)d_in[0];
    const int*   ei   = (const int*)d_in[1];
    const float* W1l  = (const float*)d_in[2];
    const float* b1   = (const float*)d_in[3];
    const float* W1r  = (const float*)d_in[4];
    const float* W2l  = (const float*)d_in[5];
    const float* b2   = (const float*)d_in[6];
    const float* W2r  = (const float*)d_in[7];
    const float* hw   = (const float*)d_in[8];
    const float* hb   = (const float*)d_in[9];
    float* out = (float*)d_out;

    const int M = in_sizes[0] / D_IN;       // 50000
    const int E = in_sizes[1] / 2;          // 800000
    const int* src = ei;
    const int* dst = ei + E;

    size_t off = 0;
    auto alloc = [&](size_t bytes) -> void* {
        void* p = (char*)d_ws + off;
        off += (bytes + 255) & ~(size_t)255;
        return p;
    };
    int* zero2  = (int*)alloc((size_t)2 * M * 4);   // deg | cursor, one memset
    int* deg    = zero2;
    int* cursor = zero2 + M;
    int* rp     = (int*)alloc((size_t)(M + 1) * 4);
    int* bsum   = (int*)alloc(256 * 4);
    int* col    = (int*)alloc((size_t)E * 4);
    unsigned short* xb    = (unsigned short*)alloc((size_t)M * D_IN * 2);
    unsigned short* w1lb  = (unsigned short*)alloc((size_t)D_H * D_IN * 2);
    unsigned short* w1rb  = (unsigned short*)alloc((size_t)D_H * D_IN * 2);
    unsigned short* w2lb  = (unsigned short*)alloc((size_t)D_H * D_H * 2);
    unsigned short* w2rb  = (unsigned short*)alloc((size_t)D_H * D_H * 2);
    unsigned short* mean1 = (unsigned short*)alloc((size_t)M * D_IN * 2);
    unsigned short* h1    = (unsigned short*)alloc((size_t)M * D_H * 2);
    unsigned short* mean2 = (unsigned short*)alloc((size_t)M * D_H * 2);

    hipMemsetAsync(zero2, 0, (size_t)2 * M * 4, stream);

    // CSR
    const int nseg = (M + 2047) / 2048;     // 25
    hist_k<<<512, 256, 0, stream>>>(dst, deg, E);
    scan_part_k<<<nseg, 256, 0, stream>>>(deg, bsum, M);
    scan_final_k<<<nseg, 256, 0, stream>>>(deg, bsum, rp, M, E);
    scatter_k<<<512, 256, 0, stream>>>(src, dst, rp, cursor, col, E);

    // bf16 conversions (x + all weights, one dispatch)
    {
        const int nx4 = (M * D_IN) / 4;
        const int nw14 = (D_H * D_IN) / 4;
        const int nw24 = (D_H * D_H) / 4;
        const int tot = nx4 + 2 * nw14 + 2 * nw24;
        f2bf_all_k<<<(tot + 255) / 256, 256, 0, stream>>>(
            x, xb, nx4, W1l, w1lb, W1r, w1rb, nw14, W2l, w2lb, W2r, w2rb, nw24);
    }

    const int nblk = (M + 63) / 64;
    const int ablk = (M + 3) / 4;

    // layer 1
    aggregate_v3<D_IN><<<ablk, 256, 0, stream>>>(xb, col, rp, mean1, M);
    gemm_mfma_k<D_IN, false><<<nblk, 256, 0, stream>>>(
        mean1, w1lb, xb, w1rb, b1, h1, nullptr, nullptr, nullptr, M);

    // layer 2 + fused head
    aggregate_v3<D_H><<<ablk, 256, 0, stream>>>(h1, col, rp, mean2, M);
    gemm_mfma_k<D_H, true><<<nblk, 256, 0, stream>>>(
        mean2, w2lb, h1, w2rb, b2, nullptr, hw, hb, out, M);
}